// Round 10
// baseline (595.298 us; speedup 1.0000x reference)
//
#include <hip/hip_runtime.h>

#define DD 128

typedef __bf16 bf16x8 __attribute__((ext_vector_type(8)));
typedef float  f32x4  __attribute__((ext_vector_type(4)));

__device__ __forceinline__ float lrelu(float x){ return x >= 0.f ? x : 0.2f*x; }
__device__ __forceinline__ float bflo(unsigned u){ return __uint_as_float(u << 16); }
__device__ __forceinline__ float bfhi(unsigned u){ return __uint_as_float(u & 0xffff0000u); }
__device__ __forceinline__ float red16(float v){
  v += __shfl_xor(v,1); v += __shfl_xor(v,2);
  v += __shfl_xor(v,4); v += __shfl_xor(v,8);
  return v;
}

// ---------------- CSR build ----------------
__global__ void k_deg_init(int* deg, int n){
  int i = blockIdx.x*blockDim.x + threadIdx.x;
  if (i < n) deg[i] = 1; // self loop
}
__global__ void k_deg_hist(const int* __restrict__ dst, int* __restrict__ deg, int E){
  int base = (blockIdx.x*blockDim.x + threadIdx.x)*4;
  if (base + 4 <= E){
    int4 d = *(const int4*)(dst + base);
    atomicAdd(&deg[d.x], 1);
    atomicAdd(&deg[d.y], 1);
    atomicAdd(&deg[d.z], 1);
    atomicAdd(&deg[d.w], 1);
  } else {
    for (int e = base; e < E; ++e) atomicAdd(&deg[dst[e]], 1);
  }
}
__global__ void k_scan_partial(const int* __restrict__ deg, int* __restrict__ partial, int n){
  __shared__ int s[128];
  int i = blockIdx.x*128 + threadIdx.x;
  int v = (i < n) ? deg[i] : 0;
  s[threadIdx.x] = v; __syncthreads();
  for (int off = 64; off; off >>= 1){
    if (threadIdx.x < off) s[threadIdx.x] += s[threadIdx.x + off];
    __syncthreads();
  }
  if (threadIdx.x == 0) partial[blockIdx.x] = s[0];
}
__global__ void k_scan_top(int* partial, int nChunks){
  __shared__ int s[512];
  int v = (threadIdx.x < nChunks) ? partial[threadIdx.x] : 0;
  s[threadIdx.x] = v; __syncthreads();
  for (int off = 1; off < 512; off <<= 1){
    int t = (threadIdx.x >= (unsigned)off) ? s[threadIdx.x - off] : 0;
    __syncthreads();
    s[threadIdx.x] += t;
    __syncthreads();
  }
  if (threadIdx.x < nChunks) partial[threadIdx.x] = s[threadIdx.x] - v; // exclusive
}
__global__ void k_scan_final(const int* __restrict__ deg, const int* __restrict__ partial,
                             int* __restrict__ rowptr, int* __restrict__ wptr, int n){
  __shared__ int s[128];
  int i = blockIdx.x*128 + threadIdx.x;
  int v = (i < n) ? deg[i] : 0;
  s[threadIdx.x] = v; __syncthreads();
  for (int off = 1; off < 128; off <<= 1){
    int t = (threadIdx.x >= (unsigned)off) ? s[threadIdx.x - off] : 0;
    __syncthreads();
    s[threadIdx.x] += t;
    __syncthreads();
  }
  int excl = s[threadIdx.x] - v + partial[blockIdx.x];
  if (i < n){
    rowptr[i] = excl; wptr[i] = excl;
    if (i == n-1) rowptr[n] = excl + v;
  }
}
// 4 edges per thread: 4 independent atomic chains in flight
__global__ void k_scatter(const int* __restrict__ src, const int* __restrict__ dst,
                          int* __restrict__ wptr, int* __restrict__ col, int E, int n){
  const int total = E + n;
  int base = (blockIdx.x*blockDim.x + threadIdx.x)*4;
  if (base >= total) return;
  int d[4], s[4]; bool ok[4];
  if (base + 4 <= E){
    int4 dv = *(const int4*)(dst + base);
    int4 sv = *(const int4*)(src + base);
    d[0]=dv.x; d[1]=dv.y; d[2]=dv.z; d[3]=dv.w;
    s[0]=sv.x; s[1]=sv.y; s[2]=sv.z; s[3]=sv.w;
    ok[0]=ok[1]=ok[2]=ok[3]=true;
  } else {
    #pragma unroll
    for (int q = 0; q < 4; ++q){
      int e = base + q;
      ok[q] = e < total;
      if (!ok[q]){ d[q]=0; s[q]=0; }
      else if (e < E){ d[q]=dst[e]; s[q]=src[e]; }
      else { d[q]=e-E; s[q]=e-E; }
    }
  }
  int p[4];
  #pragma unroll
  for (int q = 0; q < 4; ++q) if (ok[q]) p[q] = atomicAdd(&wptr[d[q]], 1);
  #pragma unroll
  for (int q = 0; q < 4; ++q) if (ok[q]) col[p[q]] = s[q];
}

// ---------------- weight prep: bf16 hi/lo col-major (B^T) for MFMA ----------------
__global__ void k_wprep(const float* __restrict__ Win, const float* __restrict__ linW,
                        __bf16* __restrict__ wt){
  int idx = blockIdx.x*256 + threadIdx.x;     // 4 * 16384 threads
  int m = idx >> 14, r = idx & 16383;
  int k = r >> 7, c = r & 127;
  const float* src = (m == 0) ? Win : linW + (size_t)(m-1)*DD*DD;
  float w = src[(size_t)k*DD + c];
  __bf16 hi = (__bf16)w;
  __bf16 lo = (__bf16)(w - (float)hi);
  wt[(size_t)(2*m  )*DD*DD + (size_t)c*DD + k] = hi;
  wt[(size_t)(2*m+1)*DD*DD + (size_t)c*DD + k] = lo;
}

// ---------------- MFMA matmul (3-term hi/lo): out = hin @ W (+bias) ----------------
template<int OUTF32>
__global__ __launch_bounds__(256) void k_mm_mfma(const float* __restrict__ hin,
    const __bf16* __restrict__ Wt, const float* __restrict__ bias,
    float* __restrict__ outf, __bf16* __restrict__ outb,
    const float* __restrict__ att_s, const float* __restrict__ att_d,
    float* __restrict__ es, float* __restrict__ ed, int n, int N)
{
  const int tid = threadIdx.x;
  const int wv  = tid >> 6, l = tid & 63;
  const int lr = l & 15, lk = l >> 4;
  const int row0 = blockIdx.x*32 + (wv >> 1)*16;
  const int ct0  = (wv & 1)*4;
  int arow = row0 + lr; if (arow >= n) arow = n - 1;
  const float* hp = hin + (size_t)arow*DD + lk*8;
  bf16x8 ah[4], al[4];
  #pragma unroll
  for (int kc = 0; kc < 4; ++kc){
    float4 lo4 = *(const float4*)(hp + kc*32);
    float4 hi4 = *(const float4*)(hp + kc*32 + 4);
    float vv[8] = {lo4.x,lo4.y,lo4.z,lo4.w,hi4.x,hi4.y,hi4.z,hi4.w};
    bf16x8 vh, vl;
    #pragma unroll
    for (int q = 0; q < 8; ++q){
      __bf16 h = (__bf16)vv[q];
      vh[q] = h;
      vl[q] = (__bf16)(vv[q] - (float)h);
    }
    ah[kc] = vh; al[kc] = vl;
  }
  f32x4 acc[4];
  #pragma unroll
  for (int ct = 0; ct < 4; ++ct) acc[ct] = (f32x4){0.f,0.f,0.f,0.f};
  const __bf16* wp = Wt + (size_t)lr*DD + lk*8;
  #pragma unroll
  for (int ct = 0; ct < 4; ++ct){
    const __bf16* wpc = wp + (size_t)(ct0+ct)*16*DD;
    #pragma unroll
    for (int kc = 0; kc < 4; ++kc){
      bf16x8 bh = *(const bf16x8*)(wpc + (size_t)kc*32);
      bf16x8 bl = *(const bf16x8*)(wpc + DD*DD + (size_t)kc*32);
      acc[ct] = __builtin_amdgcn_mfma_f32_16x16x32_bf16(ah[kc], bh, acc[ct], 0, 0, 0);
      acc[ct] = __builtin_amdgcn_mfma_f32_16x16x32_bf16(al[kc], bh, acc[ct], 0, 0, 0);
      acc[ct] = __builtin_amdgcn_mfma_f32_16x16x32_bf16(ah[kc], bl, acc[ct], 0, 0, 0);
    }
  }
  const int orow0 = row0 + lk*4;
  #pragma unroll
  for (int ct = 0; ct < 4; ++ct){
    const int colc = (ct0+ct)*16 + lr;
    float badd = 0.f;
    if (OUTF32) badd = bias[colc];
    #pragma unroll
    for (int q = 0; q < 4; ++q){
      int row = orow0 + q;
      if (row < n){
        if (OUTF32) outf[(size_t)row*DD + colc] = acc[ct][q] + badd;
        else        outb[(size_t)row*DD + colc] = (__bf16)acc[ct][q];
      }
    }
  }
  if (!OUTF32){
    float as4[4], ad4[4];
    #pragma unroll
    for (int ct = 0; ct < 4; ++ct){
      int colc = (ct0+ct)*16 + lr;
      as4[ct] = att_s[colc];
      ad4[ct] = att_d[colc];
    }
    float psA[4], psB[4], pdA[4], pdB[4];
    #pragma unroll
    for (int q = 0; q < 4; ++q){
      psA[q] = red16(acc[0][q]*as4[0] + acc[1][q]*as4[1]);
      psB[q] = red16(acc[2][q]*as4[2] + acc[3][q]*as4[3]);
      pdA[q] = red16(acc[0][q]*ad4[0] + acc[1][q]*ad4[1]);
      pdB[q] = red16(acc[2][q]*ad4[2] + acc[3][q]*ad4[3]);
    }
    if (lr == 0){
      const int hA = ct0 >> 1, hB = hA + 1;
      #pragma unroll
      for (int q = 0; q < 4; ++q){
        int row = orow0 + q;
        if (row < n){
          es[(size_t)hA*N + row] = psA[q];
          es[(size_t)hB*N + row] = psB[q];
          ed[(size_t)hA*N + row] = pdA[q];
          ed[(size_t)hB*N + row] = pdB[q];
        }
      }
    }
  }
}

// ---------------- aggregation + softmax(no-max) + bias + LN + relu + residual ----------------
// 1 wave per dst node; lane owns dims 2*lane, 2*lane+1 (head = lane>>4).
// Edge indices are wave-uniform -> readfirstlane forces SGPR addressing
// (SALU address math + saddr gathers + s_load logits), cutting per-edge VALU.
__global__ __launch_bounds__(256) void k_agg(const unsigned* __restrict__ xp,
    const float* __restrict__ es, const float* __restrict__ ed,
    const int* __restrict__ rowptr, const int* __restrict__ col,
    const float* __restrict__ cb, const float* __restrict__ lg, const float* __restrict__ lb,
    float* __restrict__ h, int n, int N)
{
  int wid = (blockIdx.x * blockDim.x + threadIdx.x) >> 6;
  int lane = threadIdx.x & 63;
  if (wid >= n) return;
  const int i = wid;
  const int rs = rowptr[i], re = rowptr[i+1];
  const int hsel = lane >> 4;
  const float* esh = es + (size_t)hsel*N;
  const float edd = ed[(size_t)hsel*N + i];
  float z = 0.f, a0 = 0.f, a1 = 0.f;
  const int slast = __builtin_amdgcn_readfirstlane(col[re-1]); // >=1 self-loop per node
  for (int j = rs; j < re; j += 8){
    int s[8]; bool ok[8];
    #pragma unroll
    for (int q = 0; q < 8; ++q){
      int jq = j + q;
      ok[q] = jq < re;
      s[q] = __builtin_amdgcn_readfirstlane(ok[q] ? col[jq] : slast);
    }
    unsigned u[8]; float e[8];
    #pragma unroll
    for (int q = 0; q < 8; ++q) u[q] = xp[(size_t)s[q]*64 + lane];
    #pragma unroll
    for (int q = 0; q < 8; ++q) e[q] = esh[s[q]];
    #pragma unroll
    for (int q = 0; q < 8; ++q){
      float w = ok[q] ? __expf(lrelu(e[q] + edd)) : 0.f;
      z += w;
      a0 = fmaf(bflo(u[q]), w, a0);
      a1 = fmaf(bfhi(u[q]), w, a1);
    }
  }
  float zi = 1.f / z;
  float2 cbv = *(const float2*)(cb + 2*lane);
  float c0 = a0*zi + cbv.x;
  float c1 = a1*zi + cbv.y;
  // LayerNorm over 128 dims (2 per lane)
  float sum = c0 + c1, sq = c0*c0 + c1*c1;
  #pragma unroll
  for (int off = 1; off < 64; off <<= 1){
    sum += __shfl_xor(sum, off);
    sq  += __shfl_xor(sq,  off);
  }
  float mu  = sum * (1.f/128.f);
  float var = sq  * (1.f/128.f) - mu*mu;
  float rinv = rsqrtf(var + 1e-5f);
  float2 lgv = *(const float2*)(lg + 2*lane);
  float2 lbv = *(const float2*)(lb + 2*lane);
  float y0 = (c0 - mu)*rinv*lgv.x + lbv.x;
  float y1 = (c1 - mu)*rinv*lgv.y + lbv.y;
  float2 rv = *(const float2*)(h + (size_t)i*DD + 2*lane);
  float2 o;
  o.x = fmaxf(y0, 0.f) + rv.x;
  o.y = fmaxf(y1, 0.f) + rv.y;
  *(float2*)(h + (size_t)i*DD + 2*lane) = o;
}

// ---------------- pooling (batch sorted): 8 nodes/block ----------------
__global__ void k_pool(const float* __restrict__ h, const int* __restrict__ batch,
                       float* __restrict__ pooled, float* __restrict__ cnt, int n){
  int d = threadIdx.x; // 128 threads
  int n0 = blockIdx.x * 8;
  if (n0 >= n) return;
  int n1 = min(n0 + 8, n);
  float acc = 0.f, cacc = 0.f; int cur = batch[n0];
  for (int i = n0; i < n1; ++i){
    int g = batch[i];
    float v = h[(size_t)i*DD + d];
    if (g != cur){
      atomicAdd(&pooled[cur*DD + d], acc);
      if (d == 0) atomicAdd(&cnt[cur], cacc);
      acc = 0.f; cacc = 0.f; cur = g;
    }
    acc += v;
    cacc += 1.f;
  }
  atomicAdd(&pooled[cur*DD + d], acc);
  if (d == 0) atomicAdd(&cnt[cur], cacc);
}

// ---------------- final MLP ----------------
__global__ void k_mlp(const float* __restrict__ pooled, const float* __restrict__ cnt,
                      const float* __restrict__ W1, const float* __restrict__ b1,
                      const float* __restrict__ W2, const float* __restrict__ b2,
                      float* __restrict__ out, int G_){
  int g = blockIdx.x, lane = threadIdx.x; // 64 threads
  float inv = 1.f / fmaxf(cnt[g], 1.f);
  float acc = b1[lane];
  for (int k = 0; k < DD; ++k)
    acc = fmaf(pooled[g*DD + k]*inv, W1[k*64 + lane], acc);
  float hv = fmaxf(acc, 0.f) * W2[lane];
  #pragma unroll
  for (int off = 32; off; off >>= 1) hv += __shfl_down(hv, off);
  if (lane == 0) out[g] = hv + b2[0];
}

extern "C" void kernel_launch(void* const* d_in, const int* in_sizes, int n_in,
                              void* d_out, int out_size, void* d_ws, size_t ws_size,
                              hipStream_t stream){
  const float* x       = (const float*)d_in[0];
  const int*   ei      = (const int*)d_in[1];
  const int*   batch   = (const int*)d_in[2];
  const float* W_in    = (const float*)d_in[3];
  const float* b_in    = (const float*)d_in[4];
  const float* lin_W   = (const float*)d_in[5];
  const float* att_src = (const float*)d_in[6];
  const float* att_dst = (const float*)d_in[7];
  const float* conv_b  = (const float*)d_in[8];
  const float* ln_g    = (const float*)d_in[9];
  const float* ln_b    = (const float*)d_in[10];
  const float* W1      = (const float*)d_in[11];
  const float* b1      = (const float*)d_in[12];
  const float* W2      = (const float*)d_in[13];
  const float* b2      = (const float*)d_in[14];
  float* outp = (float*)d_out;

  const int N = in_sizes[0] / DD;
  const int E = in_sizes[1] / 2;
  const int G = out_size;
  const int L = 3;
  const int* srcp = ei;
  const int* dstp = ei + E;

  size_t off = 0;
  auto alloc = [&](size_t bytes) -> void* {
    void* p = (char*)d_ws + off;
    off += (bytes + 255) & ~(size_t)255;
    return p;
  };
  float*  h      = (float*) alloc((size_t)N*DD*4);
  __bf16* xhb    = (__bf16*)alloc((size_t)N*DD*2);
  float*  es     = (float*) alloc((size_t)N*4*4);   // head-major [4][N]
  float*  ed     = (float*) alloc((size_t)N*4*4);   // head-major [4][N]
  int*    deg    = (int*)   alloc((size_t)N*4);
  int*    rowptr = (int*)   alloc((size_t)(N+1)*4);
  int*    wptr   = (int*)   alloc((size_t)(N+1)*4);
  int*    col    = (int*)   alloc((size_t)(E+N)*4);
  int*    partial= (int*)   alloc(512*4);
  __bf16* wt     = (__bf16*)alloc((size_t)8*DD*DD*2); // 4 matrices x {hi,lo} planes
  float*  pooled = (float*) alloc((size_t)G*DD*4);
  float*  cnt    = (float*) alloc((size_t)G*4);

  const int nChunks = (N + 127)/128;

  // CSR build
  k_deg_init<<<(N+255)/256, 256, 0, stream>>>(deg, N);
  k_deg_hist<<<(E/4+255)/256, 256, 0, stream>>>(dstp, deg, E);
  k_scan_partial<<<nChunks, 128, 0, stream>>>(deg, partial, N);
  k_scan_top<<<1, 512, 0, stream>>>(partial, nChunks);
  k_scan_final<<<nChunks, 128, 0, stream>>>(deg, partial, rowptr, wptr, N);
  k_scatter<<<((E+N)/4+255)/256, 256, 0, stream>>>(srcp, dstp, wptr, col, E, N);

  // weight prep (bf16 hi/lo transposed)
  k_wprep<<<256, 256, 0, stream>>>(W_in, lin_W, wt);

  // input projection (f32 out + bias)
  k_mm_mfma<1><<<(N+31)/32, 256, 0, stream>>>(x, wt, b_in, h, nullptr,
                                              nullptr, nullptr, nullptr, nullptr, N, N);

  // layers
  for (int l = 0; l < L; ++l){
    k_mm_mfma<0><<<(N+31)/32, 256, 0, stream>>>(h, wt + (size_t)2*(1+l)*DD*DD, nullptr,
                                                nullptr, xhb,
                                                att_src + l*DD, att_dst + l*DD, es, ed, N, N);
    k_agg<<<(N+3)/4, 256, 0, stream>>>((const unsigned*)xhb, es, ed, rowptr, col,
                                       conv_b + l*DD, ln_g + l*DD, ln_b + l*DD, h, N, N);
  }

  // pooling + MLP
  hipMemsetAsync(pooled, 0, (size_t)G*DD*4, stream);
  hipMemsetAsync(cnt,    0, (size_t)G*4,    stream);
  k_pool<<<(N+7)/8, 128, 0, stream>>>(h, batch, pooled, cnt, N);
  k_mlp<<<G, 64, 0, stream>>>(pooled, cnt, W1, b1, W2, b2, outp, G);
}

// Round 12
// 546.371 us; speedup vs baseline: 1.0895x; 1.0895x over previous
//
#include <hip/hip_runtime.h>

#define DD 128

typedef __bf16 bf16x8 __attribute__((ext_vector_type(8)));
typedef float  f32x4  __attribute__((ext_vector_type(4)));

__device__ __forceinline__ float lrelu(float x){ return x >= 0.f ? x : 0.2f*x; }
__device__ __forceinline__ float bflo(unsigned u){ return __uint_as_float(u << 16); }
__device__ __forceinline__ float bfhi(unsigned u){ return __uint_as_float(u & 0xffff0000u); }
__device__ __forceinline__ float red16(float v){
  v += __shfl_xor(v,1); v += __shfl_xor(v,2);
  v += __shfl_xor(v,4); v += __shfl_xor(v,8);
  return v;
}

// ---------------- CSR build ----------------
__global__ void k_deg_init(int* deg, int n){
  int i = blockIdx.x*blockDim.x + threadIdx.x;
  if (i < n) deg[i] = 1; // self loop
}
__global__ void k_deg_hist(const int* __restrict__ dst, int* __restrict__ deg, int E){
  int base = (blockIdx.x*blockDim.x + threadIdx.x)*4;
  if (base + 4 <= E){
    int4 d = *(const int4*)(dst + base);
    atomicAdd(&deg[d.x], 1);
    atomicAdd(&deg[d.y], 1);
    atomicAdd(&deg[d.z], 1);
    atomicAdd(&deg[d.w], 1);
  } else {
    for (int e = base; e < E; ++e) atomicAdd(&deg[dst[e]], 1);
  }
}
__global__ void k_scan_partial(const int* __restrict__ deg, int* __restrict__ partial, int n){
  __shared__ int s[128];
  int i = blockIdx.x*128 + threadIdx.x;
  int v = (i < n) ? deg[i] : 0;
  s[threadIdx.x] = v; __syncthreads();
  for (int off = 64; off; off >>= 1){
    if (threadIdx.x < off) s[threadIdx.x] += s[threadIdx.x + off];
    __syncthreads();
  }
  if (threadIdx.x == 0) partial[blockIdx.x] = s[0];
}
__global__ void k_scan_top(int* partial, int nChunks){
  __shared__ int s[512];
  int v = (threadIdx.x < nChunks) ? partial[threadIdx.x] : 0;
  s[threadIdx.x] = v; __syncthreads();
  for (int off = 1; off < 512; off <<= 1){
    int t = (threadIdx.x >= (unsigned)off) ? s[threadIdx.x - off] : 0;
    __syncthreads();
    s[threadIdx.x] += t;
    __syncthreads();
  }
  if (threadIdx.x < nChunks) partial[threadIdx.x] = s[threadIdx.x] - v; // exclusive
}
__global__ void k_scan_final(const int* __restrict__ deg, const int* __restrict__ partial,
                             int* __restrict__ rowptr, int* __restrict__ wptr, int n){
  __shared__ int s[128];
  int i = blockIdx.x*128 + threadIdx.x;
  int v = (i < n) ? deg[i] : 0;
  s[threadIdx.x] = v; __syncthreads();
  for (int off = 1; off < 128; off <<= 1){
    int t = (threadIdx.x >= (unsigned)off) ? s[threadIdx.x - off] : 0;
    __syncthreads();
    s[threadIdx.x] += t;
    __syncthreads();
  }
  int excl = s[threadIdx.x] - v + partial[blockIdx.x];
  if (i < n){
    rowptr[i] = excl; wptr[i] = excl;
    if (i == n-1) rowptr[n] = excl + v;
  }
}
// 4 edges per thread: 4 independent atomic chains in flight
__global__ void k_scatter(const int* __restrict__ src, const int* __restrict__ dst,
                          int* __restrict__ wptr, int* __restrict__ col, int E, int n){
  const int total = E + n;
  int base = (blockIdx.x*blockDim.x + threadIdx.x)*4;
  if (base >= total) return;
  int d[4], s[4]; bool ok[4];
  if (base + 4 <= E){
    int4 dv = *(const int4*)(dst + base);
    int4 sv = *(const int4*)(src + base);
    d[0]=dv.x; d[1]=dv.y; d[2]=dv.z; d[3]=dv.w;
    s[0]=sv.x; s[1]=sv.y; s[2]=sv.z; s[3]=sv.w;
    ok[0]=ok[1]=ok[2]=ok[3]=true;
  } else {
    #pragma unroll
    for (int q = 0; q < 4; ++q){
      int e = base + q;
      ok[q] = e < total;
      if (!ok[q]){ d[q]=0; s[q]=0; }
      else if (e < E){ d[q]=dst[e]; s[q]=src[e]; }
      else { d[q]=e-E; s[q]=e-E; }
    }
  }
  int p[4];
  #pragma unroll
  for (int q = 0; q < 4; ++q) if (ok[q]) p[q] = atomicAdd(&wptr[d[q]], 1);
  #pragma unroll
  for (int q = 0; q < 4; ++q) if (ok[q]) col[p[q]] = s[q];
}

// ---------------- weight prep: bf16 hi/lo col-major (B^T) for MFMA ----------------
__global__ void k_wprep(const float* __restrict__ Win, const float* __restrict__ linW,
                        __bf16* __restrict__ wt){
  int idx = blockIdx.x*256 + threadIdx.x;     // 4 * 16384 threads
  int m = idx >> 14, r = idx & 16383;
  int k = r >> 7, c = r & 127;
  const float* src = (m == 0) ? Win : linW + (size_t)(m-1)*DD*DD;
  float w = src[(size_t)k*DD + c];
  __bf16 hi = (__bf16)w;
  __bf16 lo = (__bf16)(w - (float)hi);
  wt[(size_t)(2*m  )*DD*DD + (size_t)c*DD + k] = hi;
  wt[(size_t)(2*m+1)*DD*DD + (size_t)c*DD + k] = lo;
}

// ---------------- MFMA matmul (3-term hi/lo): out = hin @ W (+bias) ----------------
template<int OUTF32>
__global__ __launch_bounds__(256) void k_mm_mfma(const float* __restrict__ hin,
    const __bf16* __restrict__ Wt, const float* __restrict__ bias,
    float* __restrict__ outf, __bf16* __restrict__ outb,
    const float* __restrict__ att_s, const float* __restrict__ att_d,
    float* __restrict__ es, float* __restrict__ ed, int n, int N)
{
  const int tid = threadIdx.x;
  const int wv  = tid >> 6, l = tid & 63;
  const int lr = l & 15, lk = l >> 4;
  const int row0 = blockIdx.x*32 + (wv >> 1)*16;
  const int ct0  = (wv & 1)*4;
  int arow = row0 + lr; if (arow >= n) arow = n - 1;
  const float* hp = hin + (size_t)arow*DD + lk*8;
  bf16x8 ah[4], al[4];
  #pragma unroll
  for (int kc = 0; kc < 4; ++kc){
    float4 lo4 = *(const float4*)(hp + kc*32);
    float4 hi4 = *(const float4*)(hp + kc*32 + 4);
    float vv[8] = {lo4.x,lo4.y,lo4.z,lo4.w,hi4.x,hi4.y,hi4.z,hi4.w};
    bf16x8 vh, vl;
    #pragma unroll
    for (int q = 0; q < 8; ++q){
      __bf16 h = (__bf16)vv[q];
      vh[q] = h;
      vl[q] = (__bf16)(vv[q] - (float)h);
    }
    ah[kc] = vh; al[kc] = vl;
  }
  f32x4 acc[4];
  #pragma unroll
  for (int ct = 0; ct < 4; ++ct) acc[ct] = (f32x4){0.f,0.f,0.f,0.f};
  const __bf16* wp = Wt + (size_t)lr*DD + lk*8;
  #pragma unroll
  for (int ct = 0; ct < 4; ++ct){
    const __bf16* wpc = wp + (size_t)(ct0+ct)*16*DD;
    #pragma unroll
    for (int kc = 0; kc < 4; ++kc){
      bf16x8 bh = *(const bf16x8*)(wpc + (size_t)kc*32);
      bf16x8 bl = *(const bf16x8*)(wpc + DD*DD + (size_t)kc*32);
      acc[ct] = __builtin_amdgcn_mfma_f32_16x16x32_bf16(ah[kc], bh, acc[ct], 0, 0, 0);
      acc[ct] = __builtin_amdgcn_mfma_f32_16x16x32_bf16(al[kc], bh, acc[ct], 0, 0, 0);
      acc[ct] = __builtin_amdgcn_mfma_f32_16x16x32_bf16(ah[kc], bl, acc[ct], 0, 0, 0);
    }
  }
  const int orow0 = row0 + lk*4;
  #pragma unroll
  for (int ct = 0; ct < 4; ++ct){
    const int colc = (ct0+ct)*16 + lr;
    float badd = 0.f;
    if (OUTF32) badd = bias[colc];
    #pragma unroll
    for (int q = 0; q < 4; ++q){
      int row = orow0 + q;
      if (row < n){
        if (OUTF32) outf[(size_t)row*DD + colc] = acc[ct][q] + badd;
        else        outb[(size_t)row*DD + colc] = (__bf16)acc[ct][q];
      }
    }
  }
  if (!OUTF32){
    float as4[4], ad4[4];
    #pragma unroll
    for (int ct = 0; ct < 4; ++ct){
      int colc = (ct0+ct)*16 + lr;
      as4[ct] = att_s[colc];
      ad4[ct] = att_d[colc];
    }
    float psA[4], psB[4], pdA[4], pdB[4];
    #pragma unroll
    for (int q = 0; q < 4; ++q){
      psA[q] = red16(acc[0][q]*as4[0] + acc[1][q]*as4[1]);
      psB[q] = red16(acc[2][q]*as4[2] + acc[3][q]*as4[3]);
      pdA[q] = red16(acc[0][q]*ad4[0] + acc[1][q]*ad4[1]);
      pdB[q] = red16(acc[2][q]*ad4[2] + acc[3][q]*ad4[3]);
    }
    if (lr == 0){
      const int hA = ct0 >> 1, hB = hA + 1;
      #pragma unroll
      for (int q = 0; q < 4; ++q){
        int row = orow0 + q;
        if (row < n){
          es[(size_t)hA*N + row] = psA[q];
          es[(size_t)hB*N + row] = psB[q];
          ed[(size_t)hA*N + row] = pdA[q];
          ed[(size_t)hB*N + row] = pdB[q];
        }
      }
    }
  }
}

// ---------------- aggregation + softmax(no-max) + bias + LN + relu + residual ----------------
// 1 wave per dst node, QUARTER-WAVE per edge: lane=(eq=lane>>4, l16=lane&15).
// Each 16-lane quarter handles one edge's full 128-dim row via one uint4 gather
// (16B/lane). exp/addr/es amortize 4x; unpack+fma at the irreducible 2/dim.
// Edge slots combined at the end with shfl_xor(16)+shfl_xor(32).
__global__ __launch_bounds__(256) void k_agg(const unsigned* __restrict__ xp,
    const float* __restrict__ es, const float* __restrict__ ed,
    const int* __restrict__ rowptr, const int* __restrict__ col,
    const float* __restrict__ cb, const float* __restrict__ lg, const float* __restrict__ lb,
    float* __restrict__ h, int n, int N)
{
  int wid = (blockIdx.x * blockDim.x + threadIdx.x) >> 6;
  int lane = threadIdx.x & 63;
  if (wid >= n) return;
  const int i = wid;
  const int rs = rowptr[i], re = rowptr[i+1];
  const int eq  = lane >> 4;   // edge slot 0..3
  const int l16 = lane & 15;   // dim group: dims 8*l16 .. 8*l16+7
  const int hsel = l16 >> 2;   // head = (8*l16)/32
  const float* esh = es + (size_t)hsel*N;
  const float edd = ed[(size_t)hsel*N + i];
  float z = 0.f;
  float a0=0.f,a1=0.f,a2=0.f,a3=0.f,a4=0.f,a5=0.f,a6=0.f,a7=0.f;
  const int slast = col[re-1]; // >=1 self-loop per node
  for (int j = rs; j < re; j += 8){
    #pragma unroll
    for (int u2 = 0; u2 < 2; ++u2){
      int jq = j + 4*u2 + eq;
      bool ok = jq < re;
      int s = ok ? col[jq] : slast;
      uint4 u = *(const uint4*)(xp + (size_t)s*64 + 4*l16);
      float e = esh[s];
      float w = ok ? __expf(lrelu(e + edd)) : 0.f;
      z += w;
      a0 = fmaf(bflo(u.x), w, a0); a1 = fmaf(bfhi(u.x), w, a1);
      a2 = fmaf(bflo(u.y), w, a2); a3 = fmaf(bfhi(u.y), w, a3);
      a4 = fmaf(bflo(u.z), w, a4); a5 = fmaf(bfhi(u.z), w, a5);
      a6 = fmaf(bflo(u.w), w, a6); a7 = fmaf(bfhi(u.w), w, a7);
    }
  }
  // combine the 4 edge slots (lanes with equal l16 share dims)
  z  += __shfl_xor(z,16);  z  += __shfl_xor(z,32);
  a0 += __shfl_xor(a0,16); a0 += __shfl_xor(a0,32);
  a1 += __shfl_xor(a1,16); a1 += __shfl_xor(a1,32);
  a2 += __shfl_xor(a2,16); a2 += __shfl_xor(a2,32);
  a3 += __shfl_xor(a3,16); a3 += __shfl_xor(a3,32);
  a4 += __shfl_xor(a4,16); a4 += __shfl_xor(a4,32);
  a5 += __shfl_xor(a5,16); a5 += __shfl_xor(a5,32);
  a6 += __shfl_xor(a6,16); a6 += __shfl_xor(a6,32);
  a7 += __shfl_xor(a7,16); a7 += __shfl_xor(a7,32);
  float zi = 1.f / z;
  float4 cb0 = *(const float4*)(cb + 8*l16);
  float4 cb1 = *(const float4*)(cb + 8*l16 + 4);
  float c0 = a0*zi + cb0.x, c1 = a1*zi + cb0.y, c2 = a2*zi + cb0.z, c3 = a3*zi + cb0.w;
  float c4 = a4*zi + cb1.x, c5 = a5*zi + cb1.y, c6 = a6*zi + cb1.z, c7 = a7*zi + cb1.w;
  // LayerNorm over 128 dims (8 per lane; all 4 quarters mirrored)
  float sum = ((c0+c1)+(c2+c3)) + ((c4+c5)+(c6+c7));
  float sq  = (c0*c0+c1*c1+c2*c2+c3*c3) + (c4*c4+c5*c5+c6*c6+c7*c7);
  #pragma unroll
  for (int off = 1; off < 16; off <<= 1){
    sum += __shfl_xor(sum, off);
    sq  += __shfl_xor(sq,  off);
  }
  float mu  = sum * (1.f/128.f);
  float var = sq  * (1.f/128.f) - mu*mu;
  float rinv = rsqrtf(var + 1e-5f);
  if (eq == 0){
    float4 lg0 = *(const float4*)(lg + 8*l16), lg1 = *(const float4*)(lg + 8*l16 + 4);
    float4 lb0 = *(const float4*)(lb + 8*l16), lb1 = *(const float4*)(lb + 8*l16 + 4);
    float4 r0 = *(const float4*)(h + (size_t)i*DD + 8*l16);
    float4 r1 = *(const float4*)(h + (size_t)i*DD + 8*l16 + 4);
    float4 o0, o1;
    o0.x = fmaxf((c0-mu)*rinv*lg0.x + lb0.x, 0.f) + r0.x;
    o0.y = fmaxf((c1-mu)*rinv*lg0.y + lb0.y, 0.f) + r0.y;
    o0.z = fmaxf((c2-mu)*rinv*lg0.z + lb0.z, 0.f) + r0.z;
    o0.w = fmaxf((c3-mu)*rinv*lg0.w + lb0.w, 0.f) + r0.w;
    o1.x = fmaxf((c4-mu)*rinv*lg1.x + lb1.x, 0.f) + r1.x;
    o1.y = fmaxf((c5-mu)*rinv*lg1.y + lb1.y, 0.f) + r1.y;
    o1.z = fmaxf((c6-mu)*rinv*lg1.z + lb1.z, 0.f) + r1.z;
    o1.w = fmaxf((c7-mu)*rinv*lg1.w + lb1.w, 0.f) + r1.w;
    *(float4*)(h + (size_t)i*DD + 8*l16)     = o0;
    *(float4*)(h + (size_t)i*DD + 8*l16 + 4) = o1;
  }
}

// ---------------- pooling (batch sorted): 8 nodes/block ----------------
__global__ void k_pool(const float* __restrict__ h, const int* __restrict__ batch,
                       float* __restrict__ pooled, float* __restrict__ cnt, int n){
  int d = threadIdx.x; // 128 threads
  int n0 = blockIdx.x * 8;
  if (n0 >= n) return;
  int n1 = min(n0 + 8, n);
  float acc = 0.f, cacc = 0.f; int cur = batch[n0];
  for (int i = n0; i < n1; ++i){
    int g = batch[i];
    float v = h[(size_t)i*DD + d];
    if (g != cur){
      atomicAdd(&pooled[cur*DD + d], acc);
      if (d == 0) atomicAdd(&cnt[cur], cacc);
      acc = 0.f; cacc = 0.f; cur = g;
    }
    acc += v;
    cacc += 1.f;
  }
  atomicAdd(&pooled[cur*DD + d], acc);
  if (d == 0) atomicAdd(&cnt[cur], cacc);
}

// ---------------- final MLP ----------------
__global__ void k_mlp(const float* __restrict__ pooled, const float* __restrict__ cnt,
                      const float* __restrict__ W1, const float* __restrict__ b1,
                      const float* __restrict__ W2, const float* __restrict__ b2,
                      float* __restrict__ out, int G_){
  int g = blockIdx.x, lane = threadIdx.x; // 64 threads
  float inv = 1.f / fmaxf(cnt[g], 1.f);
  float acc = b1[lane];
  for (int k = 0; k < DD; ++k)
    acc = fmaf(pooled[g*DD + k]*inv, W1[k*64 + lane], acc);
  float hv = fmaxf(acc, 0.f) * W2[lane];
  #pragma unroll
  for (int off = 32; off; off >>= 1) hv += __shfl_down(hv, off);
  if (lane == 0) out[g] = hv + b2[0];
}

extern "C" void kernel_launch(void* const* d_in, const int* in_sizes, int n_in,
                              void* d_out, int out_size, void* d_ws, size_t ws_size,
                              hipStream_t stream){
  const float* x       = (const float*)d_in[0];
  const int*   ei      = (const int*)d_in[1];
  const int*   batch   = (const int*)d_in[2];
  const float* W_in    = (const float*)d_in[3];
  const float* b_in    = (const float*)d_in[4];
  const float* lin_W   = (const float*)d_in[5];
  const float* att_src = (const float*)d_in[6];
  const float* att_dst = (const float*)d_in[7];
  const float* conv_b  = (const float*)d_in[8];
  const float* ln_g    = (const float*)d_in[9];
  const float* ln_b    = (const float*)d_in[10];
  const float* W1      = (const float*)d_in[11];
  const float* b1      = (const float*)d_in[12];
  const float* W2      = (const float*)d_in[13];
  const float* b2      = (const float*)d_in[14];
  float* outp = (float*)d_out;

  const int N = in_sizes[0] / DD;
  const int E = in_sizes[1] / 2;
  const int G = out_size;
  const int L = 3;
  const int* srcp = ei;
  const int* dstp = ei + E;

  size_t off = 0;
  auto alloc = [&](size_t bytes) -> void* {
    void* p = (char*)d_ws + off;
    off += (bytes + 255) & ~(size_t)255;
    return p;
  };
  float*  h      = (float*) alloc((size_t)N*DD*4);
  __bf16* xhb    = (__bf16*)alloc((size_t)N*DD*2);
  float*  es     = (float*) alloc((size_t)N*4*4);   // head-major [4][N]
  float*  ed     = (float*) alloc((size_t)N*4*4);   // head-major [4][N]
  int*    deg    = (int*)   alloc((size_t)N*4);
  int*    rowptr = (int*)   alloc((size_t)(N+1)*4);
  int*    wptr   = (int*)   alloc((size_t)(N+1)*4);
  int*    col    = (int*)   alloc((size_t)(E+N)*4);
  int*    partial= (int*)   alloc(512*4);
  __bf16* wt     = (__bf16*)alloc((size_t)8*DD*DD*2); // 4 matrices x {hi,lo} planes
  float*  pooled = (float*) alloc((size_t)G*DD*4);
  float*  cnt    = (float*) alloc((size_t)G*4);

  const int nChunks = (N + 127)/128;

  // CSR build
  k_deg_init<<<(N+255)/256, 256, 0, stream>>>(deg, N);
  k_deg_hist<<<(E/4+255)/256, 256, 0, stream>>>(dstp, deg, E);
  k_scan_partial<<<nChunks, 128, 0, stream>>>(deg, partial, N);
  k_scan_top<<<1, 512, 0, stream>>>(partial, nChunks);
  k_scan_final<<<nChunks, 128, 0, stream>>>(deg, partial, rowptr, wptr, N);
  k_scatter<<<((E+N)/4+255)/256, 256, 0, stream>>>(srcp, dstp, wptr, col, E, N);

  // weight prep (bf16 hi/lo transposed)
  k_wprep<<<256, 256, 0, stream>>>(W_in, lin_W, wt);

  // input projection (f32 out + bias)
  k_mm_mfma<1><<<(N+31)/32, 256, 0, stream>>>(x, wt, b_in, h, nullptr,
                                              nullptr, nullptr, nullptr, nullptr, N, N);

  // layers
  for (int l = 0; l < L; ++l){
    k_mm_mfma<0><<<(N+31)/32, 256, 0, stream>>>(h, wt + (size_t)2*(1+l)*DD*DD, nullptr,
                                                nullptr, xhb,
                                                att_src + l*DD, att_dst + l*DD, es, ed, N, N);
    k_agg<<<(N+3)/4, 256, 0, stream>>>((const unsigned*)xhb, es, ed, rowptr, col,
                                       conv_b + l*DD, ln_g + l*DD, ln_b + l*DD, h, N, N);
  }

  // pooling + MLP
  hipMemsetAsync(pooled, 0, (size_t)G*DD*4, stream);
  hipMemsetAsync(cnt,    0, (size_t)G*4,    stream);
  k_pool<<<(N+7)/8, 128, 0, stream>>>(h, batch, pooled, cnt, N);
  k_mlp<<<G, 64, 0, stream>>>(pooled, cnt, W1, b1, W2, b2, outp, G);
}